// Round 3
// baseline (6990.141 us; speedup 1.0000x reference)
//
#include <hip/hip_runtime.h>
#include <hip/hip_bf16.h>

#define Bc 64
#define Nn 1029
#define Dd 768
#define Hh 12
#define DH 64
#define Kk 128
#define Rr 5
#define Mm 4
#define Pp 1024
#define CTX 133
#define TWO_D 1536

typedef unsigned short u16;

__device__ __forceinline__ float bs2f(u16 u){
    union { unsigned int i; float f; } c; c.i = ((unsigned)u) << 16; return c.f;
}
__device__ __forceinline__ u16 f2bs(float f){
    unsigned int u = __float_as_uint(f);
    unsigned int r = (u + 0x7fffu + ((u >> 16) & 1u)) >> 16;  // RNE
    return (u16)r;
}

#define FMA16(acc, a, b4) do { \
    acc[0][0] += a.x*b4.x; acc[0][1] += a.x*b4.y; acc[0][2] += a.x*b4.z; acc[0][3] += a.x*b4.w; \
    acc[1][0] += a.y*b4.x; acc[1][1] += a.y*b4.y; acc[1][2] += a.y*b4.z; acc[1][3] += a.y*b4.w; \
    acc[2][0] += a.z*b4.x; acc[2][1] += a.z*b4.y; acc[2][2] += a.z*b4.z; acc[2][3] += a.z*b4.w; \
    acc[3][0] += a.w*b4.x; acc[3][1] += a.w*b4.y; acc[3][2] += a.w*b4.z; acc[3][3] += a.w*b4.w; \
} while(0)

// ---------------- K1: cls_n + argmax idx ----------------
__global__ __launch_bounds__(256)
void k_cls(const float* __restrict__ x, const float* __restrict__ cent,
           float* __restrict__ out_cls, float* __restrict__ out_idx,
           int* __restrict__ idx_i)
{
    int b = blockIdx.x, t = threadIdx.x;
    const float* xr = x + (size_t)b * Nn * Dd;
    __shared__ float sx[Dd];
    __shared__ float wred[4];
    float ss = 0.f;
    for (int i = t; i < Dd; i += 256) { float v = xr[i]; sx[i] = v; ss += v * v; }
    for (int o = 32; o > 0; o >>= 1) ss += __shfl_down(ss, o);
    int lane = t & 63, wid = t >> 6;
    if (lane == 0) wred[wid] = ss;
    __syncthreads();
    float tot = wred[0] + wred[1] + wred[2] + wred[3];
    float inv = 1.f / fmaxf(sqrtf(tot), 1e-12f);
    __syncthreads();
    for (int i = t; i < Dd; i += 256) { float v = sx[i] * inv; sx[i] = v; out_cls[(size_t)b * Dd + i] = v; }
    __syncthreads();
    float sm[Mm];
    for (int m = 0; m < Mm; m++) {
        float s = 0.f;
        for (int i = t; i < Dd; i += 256) s += sx[i] * cent[m * Dd + i];
        for (int o = 32; o > 0; o >>= 1) s += __shfl_down(s, o);
        __syncthreads();
        if (lane == 0) wred[wid] = s;
        __syncthreads();
        sm[m] = wred[0] + wred[1] + wred[2] + wred[3];
    }
    if (t == 0) {
        int best = 0; float bv = sm[0];
        for (int m = 1; m < Mm; m++) if (sm[m] > bv) { bv = sm[m]; best = m; }
        idx_i[b] = best;
        out_idx[b] = (float)best;
    }
}

// ---------------- K2: scores = Q_banks[idx] @ xp^T  (NT GEMM, fp32) ----------------
__global__ __launch_bounds__(256)
void k_scores(const float* __restrict__ x, const float* __restrict__ Qb,
              const int* __restrict__ idx_i, float* __restrict__ scores)
{
    int b = blockIdx.z;
    int k0 = blockIdx.y * 64;
    int p0 = blockIdx.x * 64;
    const float* A  = Qb + (size_t)idx_i[b] * Kk * Dd + (size_t)k0 * Dd;
    const float* Bm = x + (size_t)b * Nn * Dd + (size_t)Rr * Dd + (size_t)p0 * Dd;
    __shared__ float As[16][68] __attribute__((aligned(16)));
    __shared__ float Bs[16][68] __attribute__((aligned(16)));
    int t = threadIdx.x, tx = t & 15, ty = t >> 4;
    int lrow = t >> 2, lc4 = (t & 3) * 4;
    float acc[4][4] = {};
    for (int d0 = 0; d0 < Dd; d0 += 16) {
        float4 av = *(const float4*)(A  + (size_t)lrow * Dd + d0 + lc4);
        float4 bv = *(const float4*)(Bm + (size_t)lrow * Dd + d0 + lc4);
        As[lc4+0][lrow] = av.x; As[lc4+1][lrow] = av.y;
        As[lc4+2][lrow] = av.z; As[lc4+3][lrow] = av.w;
        Bs[lc4+0][lrow] = bv.x; Bs[lc4+1][lrow] = bv.y;
        Bs[lc4+2][lrow] = bv.z; Bs[lc4+3][lrow] = bv.w;
        __syncthreads();
        #pragma unroll
        for (int kk = 0; kk < 16; kk++) {
            float4 a  = *(const float4*)&As[kk][ty * 4];
            float4 b4 = *(const float4*)&Bs[kk][tx * 4];
            FMA16(acc, a, b4);
        }
        __syncthreads();
    }
    float* C = scores + ((size_t)b * Kk + k0) * Pp + p0;
    #pragma unroll
    for (int i = 0; i < 4; i++) {
        float4 v = make_float4(acc[i][0], acc[i][1], acc[i][2], acc[i][3]);
        *(float4*)(C + (size_t)(ty * 4 + i) * Pp + tx * 4) = v;
    }
}

// ---------------- K3: softmax rows of scores ----------------
__global__ __launch_bounds__(256)
void k_softmax(float* __restrict__ scores)
{
    size_t row = blockIdx.x;
    float* s = scores + row * Pp;
    int t = threadIdx.x;
    float v[4];
    float mx = -3.4e38f;
    #pragma unroll
    for (int j = 0; j < 4; j++) { v[j] = s[t + j * 256]; mx = fmaxf(mx, v[j]); }
    for (int o = 32; o > 0; o >>= 1) mx = fmaxf(mx, __shfl_down(mx, o));
    __shared__ float wred[4];
    int lane = t & 63, wid = t >> 6;
    if (lane == 0) wred[wid] = mx;
    __syncthreads();
    mx = fmaxf(fmaxf(wred[0], wred[1]), fmaxf(wred[2], wred[3]));
    float sum = 0.f;
    #pragma unroll
    for (int j = 0; j < 4; j++) { v[j] = __expf(v[j] - mx); sum += v[j]; }
    for (int o = 32; o > 0; o >>= 1) sum += __shfl_down(sum, o);
    __syncthreads();
    if (lane == 0) wred[wid] = sum;
    __syncthreads();
    sum = wred[0] + wred[1] + wred[2] + wred[3];
    float inv = 1.f / sum;
    #pragma unroll
    for (int j = 0; j < 4; j++) s[t + j * 256] = v[j] * inv;
}

// ---------------- K4: ctx_p = attn @ xp  (NN GEMM, fp32) ----------------
__global__ __launch_bounds__(256)
void k_ctxp(const float* __restrict__ scores, const float* __restrict__ x,
            float* __restrict__ ctx)
{
    int b = blockIdx.z;
    int k0 = blockIdx.y * 64;
    int c0 = blockIdx.x * 64;
    const float* A  = scores + ((size_t)b * Kk + k0) * Pp;
    const float* Bm = x + (size_t)b * Nn * Dd + (size_t)Rr * Dd;
    __shared__ float As[16][68] __attribute__((aligned(16)));
    __shared__ float Bs[16][68] __attribute__((aligned(16)));
    int t = threadIdx.x, tx = t & 15, ty = t >> 4;
    int arow = t >> 2, ac4 = (t & 3) * 4;
    int brow = t >> 4, bc4 = (t & 15) * 4;
    float acc[4][4] = {};
    for (int p0 = 0; p0 < Pp; p0 += 16) {
        float4 av = *(const float4*)(A + (size_t)arow * Pp + p0 + ac4);
        As[ac4+0][arow] = av.x; As[ac4+1][arow] = av.y;
        As[ac4+2][arow] = av.z; As[ac4+3][arow] = av.w;
        float4 bv = *(const float4*)(Bm + (size_t)(p0 + brow) * Dd + c0 + bc4);
        Bs[brow][bc4+0] = bv.x; Bs[brow][bc4+1] = bv.y;
        Bs[brow][bc4+2] = bv.z; Bs[brow][bc4+3] = bv.w;
        __syncthreads();
        #pragma unroll
        for (int kk = 0; kk < 16; kk++) {
            float4 a  = *(const float4*)&As[kk][ty * 4];
            float4 b4 = *(const float4*)&Bs[kk][tx * 4];
            FMA16(acc, a, b4);
        }
        __syncthreads();
    }
    float* C = ctx + ((size_t)b * CTX + Rr + k0) * Dd + c0;
    #pragma unroll
    for (int i = 0; i < 4; i++) {
        float4 v = make_float4(acc[i][0], acc[i][1], acc[i][2], acc[i][3]);
        *(float4*)(C + (size_t)(ty * 4 + i) * Dd + tx * 4) = v;
    }
}

// ---------------- K4b: copy xreg rows into ctx ----------------
__global__ __launch_bounds__(256)
void k_xreg(const float* __restrict__ x, float* __restrict__ ctx)
{
    int b = blockIdx.x, t = threadIdx.x;
    const float* src = x + (size_t)b * Nn * Dd;
    float* dst = ctx + (size_t)b * CTX * Dd;
    for (int i = t; i < Rr * Dd; i += 256) dst[i] = src[i];
}

// ---------------- K5: kv = ctx @ Wctx + bctx  (NN GEMM, fp32 in, bf16 out) ----------------
__global__ __launch_bounds__(256)
void k_kv(const float* __restrict__ ctx, const float* __restrict__ Wctx,
          const float* __restrict__ bctx, u16* __restrict__ kvb)
{
    int b = blockIdx.z;
    int m0 = blockIdx.y * 64;
    int c0 = blockIdx.x * 64;
    const float* A = ctx + (size_t)b * CTX * Dd;
    __shared__ float As[16][68] __attribute__((aligned(16)));
    __shared__ float Bs[16][68] __attribute__((aligned(16)));
    int t = threadIdx.x, tx = t & 15, ty = t >> 4;
    int arow = t >> 2, ac4 = (t & 3) * 4;
    int brow = t >> 4, bc4 = (t & 15) * 4;
    int am = m0 + arow;
    float acc[4][4] = {};
    for (int d0 = 0; d0 < Dd; d0 += 16) {
        float4 av = (am < CTX) ? *(const float4*)(A + (size_t)am * Dd + d0 + ac4)
                               : make_float4(0.f, 0.f, 0.f, 0.f);
        As[ac4+0][arow] = av.x; As[ac4+1][arow] = av.y;
        As[ac4+2][arow] = av.z; As[ac4+3][arow] = av.w;
        float4 bv = *(const float4*)(Wctx + (size_t)(d0 + brow) * TWO_D + c0 + bc4);
        Bs[brow][bc4+0] = bv.x; Bs[brow][bc4+1] = bv.y;
        Bs[brow][bc4+2] = bv.z; Bs[brow][bc4+3] = bv.w;
        __syncthreads();
        #pragma unroll
        for (int kk = 0; kk < 16; kk++) {
            float4 a  = *(const float4*)&As[kk][ty * 4];
            float4 b4 = *(const float4*)&Bs[kk][tx * 4];
            FMA16(acc, a, b4);
        }
        __syncthreads();
    }
    float bias[4];
    #pragma unroll
    for (int j = 0; j < 4; j++) bias[j] = bctx[c0 + tx * 4 + j];
    #pragma unroll
    for (int i = 0; i < 4; i++) {
        int m = m0 + ty * 4 + i;
        if (m < CTX) {
            ushort4 o;
            o.x = f2bs(acc[i][0] + bias[0]); o.y = f2bs(acc[i][1] + bias[1]);
            o.z = f2bs(acc[i][2] + bias[2]); o.w = f2bs(acc[i][3] + bias[3]);
            *(ushort4*)(kvb + ((size_t)b * CTX + m) * TWO_D + c0 + tx * 4) = o;
        }
    }
}

// ---------------- K6: fused q-projection + attention -> y (bf16) ----------------
__global__ __launch_bounds__(256)
void k_attn(const float* __restrict__ x, const float* __restrict__ Wq,
            const u16* __restrict__ kvb, u16* __restrict__ y)
{
    int b = blockIdx.z;
    int h = blockIdx.y;
    int n0 = blockIdx.x * 16;
    int t = threadIdx.x;
    int tx = t & 15, ty = t >> 4;

    __shared__ u16 ks[CTX][68] __attribute__((aligned(16)));
    __shared__ u16 vs[CTX][68] __attribute__((aligned(16)));
    __shared__ float qs[16][65];
    __shared__ float ps[16][133];
    __shared__ float xs[16][17];
    __shared__ float wqs[16][68] __attribute__((aligned(16)));

    // phase a: stage k,v (bf16 bits) into LDS
    const u16* kvrow = kvb + (size_t)b * CTX * TWO_D + h * DH;
    for (int e4 = t * 4; e4 < CTX * DH; e4 += 1024) {
        int m = e4 >> 6, dd = e4 & 63;
        *(ushort4*)&ks[m][dd] = *(const ushort4*)(kvrow + (size_t)m * TWO_D + dd);
        *(ushort4*)&vs[m][dd] = *(const ushort4*)(kvrow + (size_t)m * TWO_D + Dd + dd);
    }
    __syncthreads();

    // phase b: q_tile = x[n0:n0+16,:] @ Wq[:, h*64:(h+1)*64], scaled by 1/8
    const float* xb  = x + (size_t)b * Nn * Dd;
    const float* wqh = Wq + h * DH;
    float q0 = 0.f, q1 = 0.f, q2 = 0.f, q3 = 0.f;
    for (int d0 = 0; d0 < Dd; d0 += 16) {
        {
            int gn = n0 + ty;
            xs[tx][ty] = (gn < Nn) ? xb[(size_t)gn * Dd + d0 + tx] : 0.f;
            float4 wv = *(const float4*)(wqh + (size_t)(d0 + ty) * Dd + tx * 4);
            wqs[ty][tx*4+0] = wv.x; wqs[ty][tx*4+1] = wv.y;
            wqs[ty][tx*4+2] = wv.z; wqs[ty][tx*4+3] = wv.w;
        }
        __syncthreads();
        #pragma unroll
        for (int kk = 0; kk < 16; kk++) {
            float a = xs[kk][ty];
            float4 b4 = *(const float4*)&wqs[kk][tx * 4];
            q0 += a * b4.x; q1 += a * b4.y; q2 += a * b4.z; q3 += a * b4.w;
        }
        __syncthreads();
    }
    qs[ty][tx*4+0] = q0 * 0.125f;
    qs[ty][tx*4+1] = q1 * 0.125f;
    qs[ty][tx*4+2] = q2 * 0.125f;
    qs[ty][tx*4+3] = q3 * 0.125f;
    __syncthreads();

    // phase c: logits = qs @ ks^T  -> ps[16][133]
    for (int e = t; e < 16 * CTX; e += 256) {
        int r = e / CTX, m = e - r * CTX;
        const float* qrow = &qs[r][0];
        const u16*   krow = &ks[m][0];
        float s = 0.f;
        for (int dd = 0; dd < DH; dd++) s += qrow[dd] * bs2f(krow[dd]);
        ps[r][m] = s;
    }
    __syncthreads();

    // phase d: softmax rows of ps (16 threads per row, groups aligned to t>>4)
    {
        float mx = -3.4e38f;
        for (int m = tx; m < CTX; m += 16) mx = fmaxf(mx, ps[ty][m]);
        mx = fmaxf(mx, __shfl_xor(mx, 1, 16));
        mx = fmaxf(mx, __shfl_xor(mx, 2, 16));
        mx = fmaxf(mx, __shfl_xor(mx, 4, 16));
        mx = fmaxf(mx, __shfl_xor(mx, 8, 16));
        float sum = 0.f;
        for (int m = tx; m < CTX; m += 16) sum += __expf(ps[ty][m] - mx);
        sum += __shfl_xor(sum, 1, 16);
        sum += __shfl_xor(sum, 2, 16);
        sum += __shfl_xor(sum, 4, 16);
        sum += __shfl_xor(sum, 8, 16);
        float inv = 1.f / sum;
        for (int m = tx; m < CTX; m += 16) ps[ty][m] = __expf(ps[ty][m] - mx) * inv;
    }
    __syncthreads();

    // phase e: y_tile = ps @ vs
    {
        float y0 = 0.f, y1 = 0.f, y2 = 0.f, y3 = 0.f;
        for (int m = 0; m < CTX; m++) {
            float p = ps[ty][m];
            const u16* vrow = &vs[m][tx * 4];
            y0 += p * bs2f(vrow[0]); y1 += p * bs2f(vrow[1]);
            y2 += p * bs2f(vrow[2]); y3 += p * bs2f(vrow[3]);
        }
        int gn = n0 + ty;
        if (gn < Nn) {
            ushort4 o;
            o.x = f2bs(y0); o.y = f2bs(y1); o.z = f2bs(y2); o.w = f2bs(y3);
            *(ushort4*)(y + ((size_t)b * Nn + gn) * Dd + h * DH + tx * 4) = o;
        }
    }
}

// ---------------- K7: out = y @ Wout + bout  (y bf16, rest fp32) ----------------
__global__ __launch_bounds__(256)
void k_out(const u16* __restrict__ y, const float* __restrict__ Wout,
           const float* __restrict__ bout, float* __restrict__ outp)
{
    int r0 = blockIdx.y * 64;
    int c0 = blockIdx.x * 64;
    __shared__ float As[16][68] __attribute__((aligned(16)));
    __shared__ float Bs[16][68] __attribute__((aligned(16)));
    int t = threadIdx.x, tx = t & 15, ty = t >> 4;
    int arow = t >> 2, ac4 = (t & 3) * 4;
    int brow = t >> 4, bc4 = (t & 15) * 4;
    float acc[4][4] = {};
    const u16* Arow = y + (size_t)(r0 + arow) * Dd;
    for (int d0 = 0; d0 < Dd; d0 += 16) {
        ushort4 av = *(const ushort4*)(Arow + d0 + ac4);
        As[ac4+0][arow] = bs2f(av.x); As[ac4+1][arow] = bs2f(av.y);
        As[ac4+2][arow] = bs2f(av.z); As[ac4+3][arow] = bs2f(av.w);
        float4 bv = *(const float4*)(Wout + (size_t)(d0 + brow) * Dd + c0 + bc4);
        Bs[brow][bc4+0] = bv.x; Bs[brow][bc4+1] = bv.y;
        Bs[brow][bc4+2] = bv.z; Bs[brow][bc4+3] = bv.w;
        __syncthreads();
        #pragma unroll
        for (int kk = 0; kk < 16; kk++) {
            float4 a  = *(const float4*)&As[kk][ty * 4];
            float4 b4 = *(const float4*)&Bs[kk][tx * 4];
            FMA16(acc, a, b4);
        }
        __syncthreads();
    }
    float bias[4];
    #pragma unroll
    for (int j = 0; j < 4; j++) bias[j] = bout[c0 + tx * 4 + j];
    #pragma unroll
    for (int i = 0; i < 4; i++) {
        float4 v = make_float4(acc[i][0] + bias[0], acc[i][1] + bias[1],
                               acc[i][2] + bias[2], acc[i][3] + bias[3]);
        *(float4*)(outp + (size_t)(r0 + ty * 4 + i) * Dd + c0 + tx * 4) = v;
    }
}

extern "C" void kernel_launch(void* const* d_in, const int* in_sizes, int n_in,
                              void* d_out, int out_size, void* d_ws, size_t ws_size,
                              hipStream_t stream)
{
    const float* x    = (const float*)d_in[0];
    const float* Qb   = (const float*)d_in[1];
    const float* Wq   = (const float*)d_in[2];
    const float* Wctx = (const float*)d_in[3];
    const float* bctx = (const float*)d_in[4];
    const float* Wout = (const float*)d_in[5];
    const float* bout = (const float*)d_in[6];
    const float* cent = (const float*)d_in[7];

    float* out     = (float*)d_out;
    float* out_cls = out + (size_t)Bc * Nn * Dd;
    float* out_idx = out_cls + (size_t)Bc * Dd;

    // ws layout: [idx(1KB)] [scores fp32 33.5MB / kvb bf16 26.1MB (reused)] [ctx fp32 26.2MB] [y bf16 101.2MB]
    const size_t SC_B  = (size_t)Bc * Kk * Pp * 4;   // 33,554,432
    const size_t CTX_B = (size_t)Bc * CTX * Dd * 4;  // 26,148,864
    const size_t Y_B   = (size_t)Bc * Nn * Dd * 2;   // 101,154,816
    const size_t NEED  = 1024 + SC_B + CTX_B + Y_B;  // 160,859,136
    if (ws_size < NEED) return;  // fail loudly (zero outputs) rather than corrupt memory

    char* w = (char*)d_ws;
    int*   idx_i  = (int*)w;
    float* scores = (float*)(w + 1024);
    u16*   kvb    = (u16*)(w + 1024);               // reuses scores region after K4
    float* ctx    = (float*)(w + 1024 + SC_B);
    u16*   y      = (u16*)(w + 1024 + SC_B + CTX_B);

    k_cls    <<<Bc, 256, 0, stream>>>(x, cent, out_cls, out_idx, idx_i);
    k_scores <<<dim3(16, 2, Bc), 256, 0, stream>>>(x, Qb, idx_i, scores);
    k_softmax<<<Bc * Kk, 256, 0, stream>>>(scores);
    k_ctxp   <<<dim3(12, 2, Bc), 256, 0, stream>>>(scores, x, ctx);
    k_xreg   <<<Bc, 256, 0, stream>>>(x, ctx);
    k_kv     <<<dim3(24, 3, Bc), 256, 0, stream>>>(ctx, Wctx, bctx, kvb);
    k_attn   <<<dim3(65, Hh, Bc), 256, 0, stream>>>(x, Wq, kvb, y);
    k_out    <<<dim3(12, 1029), 256, 0, stream>>>(y, Wout, bout, out);
}